// Round 6
// baseline (1760.924 us; speedup 1.0000x reference)
//
#include <hip/hip_runtime.h>
#include <math.h>

#define CIN   128
#define HID   128
#define HDIM  64
#define WDIM  64
#define HW    4096
#define LDSROW  136    // shorts per LDS image row (128 c + 8 pad)
#define LDSROWU 68     // uints per row

typedef short short8 __attribute__((ext_vector_type(8)));
typedef float f32x4  __attribute__((ext_vector_type(4)));

__device__ __forceinline__ unsigned short f2bf(float f) {
    union { float f; unsigned int u; } v; v.f = f;
    unsigned int r = v.u + 0x7fffu + ((v.u >> 16) & 1u);   // RNE
    return (unsigned short)(r >> 16);
}
__device__ __forceinline__ unsigned int pack2bf(float a, float b) {
    return (unsigned int)f2bf(a) | ((unsigned int)f2bf(b) << 16);
}
__device__ __forceinline__ float sigm(float x)  { return 1.0f / (1.0f + __expf(-x)); }
__device__ __forceinline__ float tanhft(float x){ return 2.0f / (1.0f + __expf(-2.0f * x)) - 1.0f; }

// ---------------------------------------------------------------------------
// Pack: Wpk2 = per-wave-contiguous B-fragments.
//  flat idx = ((h16g*2+gp)*40 + ks*2 + gs)*512 + lane*8 + j
//  maps to B[n][k]: n = (gp*2+gs)*128 + h16g*16 + (lane&15),
//                   k = ks*32 + (lane>>4)*8 + j
//  k < 256: x-part (tap t=k>>7 of masked W_is), else h-part (W_ss).
//  Each wave streams one contiguous 40 KB block per row -> zero duplication.
// ---------------------------------------------------------------------------
__global__ void pack_kernel(const float* __restrict__ W_is,
                            const float* __restrict__ b_is,
                            const float* __restrict__ W_ss,
                            const float* __restrict__ b_ss,
                            unsigned short* __restrict__ Wpk2,
                            float* __restrict__ bias_p) {
    int idx = blockIdx.x * blockDim.x + threadIdx.x;
    if (idx < 640 * 512) {
        int j    = idx & 7;
        int lane = (idx >> 3) & 63;
        int f    = idx >> 9;
        int gs   = f & 1;
        int fs   = f >> 1;
        int ks   = fs % 20;
        int wgrp = fs / 20;          // h16g*2 + gp
        int gp   = wgrp & 1;
        int h16g = wgrp >> 1;
        int g    = gp * 2 + gs;
        int n    = g * 128 + h16g * 16 + (lane & 15);
        int k    = ks * 32 + (lane >> 4) * 8 + j;
        float v;
        if (k < 256) { int t = k >> 7, c = k & 127;  v = W_is[((size_t)n * CIN + c) * 3 + t]; }
        else { int kk = k - 256; int t = kk >> 7, c = kk & 127; v = W_ss[((size_t)n * HID + c) * 3 + t]; }
        Wpk2[idx] = f2bf(v);
    }
    if (idx < 512) bias_p[idx] = b_is[idx] + b_ss[idx];
}

// ---------------------------------------------------------------------------
// Persistent RowLSTM: 16 blocks (one per batch) x 1024 threads (16 waves),
// 1 block/CU, entire 64-row recurrence in one launch.
//  wave = (h16g 0..7, gp 0..1): 4 m-tiles x 2 gate-tiles, all 20 k-steps.
//  h row: bf16 image in lds_h (halo rows 0/65 stay zero) -- never leaves LDS.
//  c state: registers (f32x4 x4 on gp0 waves).
//  x row r+1: prefetched to regs during row r MFMA, converted in epilogue.
//  gate exchange: gp1 (o,g) -> lds_z -> gp0 combines + LSTM + writes h/out.
// ---------------------------------------------------------------------------
__global__ __launch_bounds__(1024, 4) void lstm_kernel(
        const float* __restrict__ x,
        const unsigned short* __restrict__ Wpk2,
        const float* __restrict__ bias_p,
        float* __restrict__ out) {
    __shared__ __align__(16) unsigned short lds_x[66 * LDSROW];  // 17.5 KB
    __shared__ __align__(16) unsigned short lds_h[66 * LDSROW];  // 17.5 KB
    __shared__ __align__(16) float lds_z[8 * 4 * 2 * 64 * 4];    // 64 KB

    const int tid  = threadIdx.x;
    const int b    = blockIdx.x;
    const int wv   = tid >> 6;
    const int lane = tid & 63;
    const int h16g = __builtin_amdgcn_readfirstlane(wv >> 1);
    const int gp   = __builtin_amdgcn_readfirstlane(wv & 1);
    const int quad = lane >> 4;
    const int l15  = lane & 15;
    const int hch  = h16g * 16 + l15;

    // zero lds_h (row-0 state + halos) and lds_x halo row 0
    for (int i = tid; i < 66 * LDSROWU; i += 1024) ((unsigned int*)lds_h)[i] = 0u;
    if (tid < LDSROWU) ((unsigned int*)lds_x)[tid] = 0u;

    const float* xb = x + (size_t)b * (CIN * HW);
    // stage x row 0: 8192 floats, 8 per thread, coalesced along w=lane
#pragma unroll
    for (int p = 0; p < 4; ++p) {
        int cp = p * 16 + wv;                 // c-pair 0..63
        float v0 = xb[(2 * cp) * HW + lane];
        float v1 = xb[(2 * cp + 1) * HW + lane];
        ((unsigned int*)lds_x)[(lane + 1) * LDSROWU + cp] = pack2bf(v0, v1);
    }
    __syncthreads();

    // this wave's contiguous 40 KB weight block; frag (ks,gs) at +(ks*2+gs)*512
    const unsigned short* wbase =
        Wpk2 + (size_t)(h16g * 2 + gp) * 40 * 512 + lane * 8;

    const float bi  = bias_p[hch];
    const float bfv = bias_p[128 + hch];
    const float bo  = bias_p[256 + hch];
    const float bg  = bias_p[384 + hch];

    f32x4 cst[4];
#pragma unroll
    for (int m = 0; m < 4; ++m) cst[m] = (f32x4){0.f, 0.f, 0.f, 0.f};

    for (int r = 0; r < HDIM; ++r) {
        // ---- prefetch x row r+1 into regs (consumed after B2) ----
        float xf[8];
        if (r < HDIM - 1) {
            const float* xr = xb + (size_t)(r + 1) * WDIM;
#pragma unroll
            for (int p = 0; p < 4; ++p) {
                int cp = p * 16 + wv;
                xf[2 * p]     = xr[(2 * cp) * HW + lane];
                xf[2 * p + 1] = xr[(2 * cp + 1) * HW + lane];
            }
        }

        // ---- MFMA: 20 k-steps x 4 m-tiles x 2 gate-tiles ----
        f32x4 acc[4][2];
#pragma unroll
        for (int m = 0; m < 4; ++m) {
            acc[m][0] = (f32x4){0.f, 0.f, 0.f, 0.f};
            acc[m][1] = (f32x4){0.f, 0.f, 0.f, 0.f};
        }
#pragma unroll
        for (int ks = 0; ks < 20; ++ks) {
            const unsigned short* abuf = (ks < 8) ? lds_x : lds_h;
            const int kk = (ks < 8) ? ks : ks - 8;
            const int t  = kk >> 2;
            const int c0 = (kk & 3) * 32;
            short8 a[4];
#pragma unroll
            for (int m = 0; m < 4; ++m)
                a[m] = *(const short8*)&abuf[(m * 16 + l15 + t) * LDSROW + c0 + quad * 8];
            short8 b0 = *(const short8*)&wbase[(ks * 2 + 0) * 512];
            short8 b1 = *(const short8*)&wbase[(ks * 2 + 1) * 512];
#pragma unroll
            for (int m = 0; m < 4; ++m) {
                acc[m][0] = __builtin_amdgcn_mfma_f32_16x16x32_bf16(a[m], b0, acc[m][0], 0, 0, 0);
                acc[m][1] = __builtin_amdgcn_mfma_f32_16x16x32_bf16(a[m], b1, acc[m][1], 0, 0, 0);
            }
        }
        __syncthreads();                       // B1: all LDS reads of row r done

        // ---- gp1 publishes z_o, z_g partials ----
        if (gp == 1) {
#pragma unroll
            for (int m = 0; m < 4; ++m) {
                *(f32x4*)&lds_z[(((h16g * 4 + m) * 2 + 0) * 64 + lane) * 4] = acc[m][0];
                *(f32x4*)&lds_z[(((h16g * 4 + m) * 2 + 1) * 64 + lane) * 4] = acc[m][1];
            }
        }
        __syncthreads();                       // B2: z visible

        // ---- stage x row r+1 (lds_x reads finished at B1) ----
        if (r < HDIM - 1) {
#pragma unroll
            for (int p = 0; p < 4; ++p)
                ((unsigned int*)lds_x)[(lane + 1) * LDSROWU + p * 16 + wv] =
                    pack2bf(xf[2 * p], xf[2 * p + 1]);
        }

        // ---- gp0: combine gates, LSTM update, write h (LDS bf16) + out ----
        if (gp == 0) {
#pragma unroll
            for (int m = 0; m < 4; ++m) {
                f32x4 zo4 = *(const f32x4*)&lds_z[(((h16g * 4 + m) * 2 + 0) * 64 + lane) * 4];
                f32x4 zg4 = *(const f32x4*)&lds_z[(((h16g * 4 + m) * 2 + 1) * 64 + lane) * 4];
                f32x4 hv;
#pragma unroll
                for (int e = 0; e < 4; ++e) {
                    float zi = acc[m][0][e] + bi;
                    float zf = acc[m][1][e] + bfv;
                    float zo = zo4[e] + bo;
                    float zg = zg4[e] + bg;
                    float ig = sigm(zi), fg = sigm(zf), og = sigm(zo);
                    float gg = tanhft(zg);
                    float cn = fg * cst[m][e] + ig * gg;
                    cst[m][e] = cn;
                    hv[e] = og * tanhft(cn);
                    lds_h[(m * 16 + quad * 4 + e + 1) * LDSROW + hch] = f2bf(hv[e]);
                }
                *(f32x4*)&out[(((size_t)b * HID + hch) * HDIM + r) * WDIM
                              + m * 16 + quad * 4] = hv;
            }
        }
        __syncthreads();                       // B3: lds_h / lds_x ready
    }
}

extern "C" void kernel_launch(void* const* d_in, const int* in_sizes, int n_in,
                              void* d_out, int out_size, void* d_ws, size_t ws_size,
                              hipStream_t stream) {
    const float* x    = (const float*)d_in[0];
    const float* W_is = (const float*)d_in[1];
    const float* b_is = (const float*)d_in[2];
    const float* W_ss = (const float*)d_in[3];
    const float* b_ss = (const float*)d_in[4];
    float* out = (float*)d_out;

    // ws: Wpk2 bf16[640*512] (655,360 B) | bias fp32[512]
    unsigned short* Wpk2   = (unsigned short*)d_ws;
    float*          bias_p = (float*)((char*)d_ws + 655360);

    pack_kernel<<<(640 * 512 + 255) / 256, 256, 0, stream>>>(
        W_is, b_is, W_ss, b_ss, Wpk2, bias_p);

    lstm_kernel<<<16, 1024, 0, stream>>>(x, Wpk2, bias_p, out);
}